// Round 1
// baseline (220.250 us; speedup 1.0000x reference)
//
#include <hip/hip_runtime.h>
#include <hip/hip_bf16.h>

#define B_  8
#define H_  512
#define L_  2048
#define D2_ 32
#define NC_ 64
#define LC_ 32    // L_/NC_
#define LCF 32    // fk kernel l-chunk

typedef __attribute__((ext_vector_type(8))) short short8;   // 8 bf16 (4 VGPRs)
typedef __attribute__((ext_vector_type(4))) float float4v;  // 4 fp32 acc
typedef __attribute__((ext_vector_type(2))) float f32x2;    // packed fp32 (v_pk_*)

__device__ __forceinline__ f32x2 pk_fma(f32x2 a, f32x2 b, f32x2 c) {
    return __builtin_elementwise_fma(a, b, c);
}

__device__ __forceinline__ float gelu_exact(float x) {
    return 0.5f * x * (1.0f + erff(x * 0.70710678118654752f));
}

__device__ __forceinline__ unsigned pack_bf16x2(float x, float y) {
    __hip_bfloat162 p = __float22bfloat162_rn(make_float2(x, y));
    return *(unsigned*)&p;
}
__device__ __forceinline__ float2 unpack_bf16x2(unsigned v) {
    __hip_bfloat162 p = *(__hip_bfloat162*)&v;
    return __bfloat1622float2(p);
}

__device__ __forceinline__ void load_lds16(const void* g, void* l) {
    __builtin_amdgcn_global_load_lds((const __attribute__((address_space(1))) unsigned int*)g,
                                     (__attribute__((address_space(3))) unsigned int*)l, 16, 0, 0);
}

// ---------------- cast W -> bf16, fused param prep ----------------
// Adds WP: per-h chunk-combine multipliers P^(2^k), P = w^32, k = 0..5.
// Layout WP[h][k][0:32]=Re, WP[h][k][32:64]=Im  (wave-uniform -> scalar loads)
__global__ void cast_prep_kernel(const float* __restrict__ W, __hip_bfloat16* __restrict__ Wb,
                                 const float* __restrict__ a, const float* __restrict__ th,
                                 const float* __restrict__ bb, const float* __restrict__ cc,
                                 const float* __restrict__ x0,
                                 float* __restrict__ aT, float* __restrict__ thT,
                                 float* __restrict__ qT, float* __restrict__ gxT,
                                 float* __restrict__ WRh, float* __restrict__ WIh,
                                 float* __restrict__ QSh, float* __restrict__ WPp) {
    int tid = blockIdx.x * 256 + threadIdx.x;   // 262144
    Wb[tid] = __float2bfloat16(W[tid]);
    if (tid < H_ * D2_) {                        // tid = d*H + h (d-major)
        int h = tid & (H_ - 1);
        int d = tid >> 9;
        const float T = 1.0f / (float)(L_ - 1);
        float av = -fabsf(a[h * D2_ + d]);
        float tv = th[h * D2_ + d];
        float q  = bb[h * D2_ + d] * cc[h * D2_ + d];
        float e  = __expf(av * T);
        aT[tid]  = av;
        thT[tid] = tv;
        qT[tid]  = q;
        gxT[tid] = 2.0f * cc[h * D2_ + d] * x0[h * D2_ + d];
        WRh[h * D2_ + d] = e * __cosf(tv * T);   // h-major for scan kernels
        WIh[h * D2_ + d] = e * __sinf(tv * T);
        QSh[h * D2_ + d] = 2.0f * T * q;
        #pragma unroll
        for (int k = 0; k < 6; ++k) {
            float len = (float)(32 << k);        // 32 * 2^k steps
            float e2  = __expf(av * T * len);
            float an  = tv * T * len;
            WPp[((size_t)h * 6 + k) * 64 + d]      = e2 * __cosf(an);
            WPp[((size_t)h * 6 + k) * 64 + 32 + d] = e2 * __sinf(an);
        }
    }
}

// ---------------- fk: FKf[h*L + l] = bf16x2{ f[h,l], k0[h,l] } ----------------
__global__ __launch_bounds__(256) void fk_kernel(
        const float* __restrict__ aT, const float* __restrict__ thT,
        const float* __restrict__ qT, const float* __restrict__ gxT,
        unsigned* __restrict__ FKf) {
    int t = threadIdx.x;
    int q4 = t & 3, hl = t >> 2;
    int h  = blockIdx.y * 64 + hl;
    int l0 = blockIdx.x * LCF;
    const float T = 1.0f / (float)(L_ - 1);
    float z0 = T * (float)l0;
    float pr[8], pi[8], wr[8], wi[8], qd[8], gx[8];
    #pragma unroll
    for (int j = 0; j < 8; ++j) {
        int idx = (q4 * 8 + j) * H_ + h;
        float aa = aT[idx], tv = thT[idx];
        float e0 = __expf(aa * z0);
        pr[j] = e0 * __cosf(tv * z0);
        pi[j] = e0 * __sinf(tv * z0);
        float e1 = __expf(aa * T);
        wr[j] = e1 * __cosf(tv * T);
        wi[j] = e1 * __sinf(tv * T);
        qd[j] = qT[idx];
        gx[j] = gxT[idx];
    }
    for (int i = 0; i < LCF; ++i) {
        float fa = 0.f, ka = 0.f;
        #pragma unroll
        for (int j = 0; j < 8; ++j) {
            fa = fmaf(qd[j], pr[j], fa);
            ka = fmaf(gx[j], pr[j], ka);
            float nr = fmaf(pr[j], wr[j], -(pi[j] * wi[j]));
            float ni = fmaf(pr[j], wi[j],  (pi[j] * wr[j]));
            pr[j] = nr; pi[j] = ni;
        }
        fa += __shfl_xor(fa, 1); fa += __shfl_xor(fa, 2);
        ka += __shfl_xor(ka, 1); ka += __shfl_xor(ka, 2);
        if (q4 == 0)
            FKf[(size_t)h * L_ + l0 + i] = pack_bf16x2(2.0f * T * fa, ka);
    }
}

// ---------------- fused scan: phase A (local end states) -> wave prefix scan
//                  (Hillis-Steele over lanes=chunks) -> phase B (outputs).
// No LDS: each lane's chunk of u / FKf is exactly one 128B cache line.
// Carries stay fp32 in registers (previously bf16 via E round-trip).
__global__ __launch_bounds__(128) void scan_fused_kernel(
        const float* __restrict__ u, const float* __restrict__ WRh,
        const float* __restrict__ WIh, const float* __restrict__ QSh,
        const float* __restrict__ WPp, const float* __restrict__ Dp,
        const unsigned* __restrict__ FKf, __hip_bfloat16* __restrict__ y) {
    int wave = threadIdx.x >> 6;
    int c    = threadIdx.x & 63;        // lane = chunk
    int h = blockIdx.x * 2 + wave;
    int b = blockIdx.y;
    const float* ug = u + (size_t)(b * H_ + h) * L_ + c * LC_;

    // wave-uniform params -> SGPRs
    f32x2 wr2[16], wi2[16], qs2[16];
    float f0 = 0.f;
    #pragma unroll
    for (int j = 0; j < 16; ++j) {
        float2 wrv = *(const float2*)(WRh + h * D2_ + 2 * j);
        float2 wiv = *(const float2*)(WIh + h * D2_ + 2 * j);
        float2 qv  = *(const float2*)(QSh + h * D2_ + 2 * j);
        wr2[j] = (f32x2){wrv.x, wrv.y};
        wi2[j] = (f32x2){wiv.x, wiv.y};
        qs2[j] = (f32x2){qv.x, qv.y};
        f0 += qv.x + qv.y;
    }
    float Dh = Dp[h];
    float c0 = Dh - 0.5f * f0;          // coeff of u[l]

    // ---- phase A: local recurrence from zero -> chunk end state ----
    float4 ua[8];
    #pragma unroll
    for (int k = 0; k < 8; ++k) ua[k] = ((const float4*)ug)[k];
    float u0 = __shfl(ua[0].x, 0);      // u[bh*L + 0]
    float c1 = -0.5f * u0;              // coeff of f[l]

    f32x2 sr2[16], si2[16];
    #pragma unroll
    for (int j = 0; j < 16; ++j) { sr2[j] = (f32x2){0.f, 0.f}; si2[j] = (f32x2){0.f, 0.f}; }
    #pragma unroll
    for (int k = 0; k < 8; ++k) {
        float us[4] = {ua[k].x, ua[k].y, ua[k].z, ua[k].w};
        #pragma unroll
        for (int e = 0; e < 4; ++e) {
            f32x2 ul2 = (f32x2){us[e], us[e]};
            #pragma unroll
            for (int j = 0; j < 16; ++j) {
                f32x2 nr = pk_fma(sr2[j], wr2[j], pk_fma(-si2[j], wi2[j], ul2));
                f32x2 ni = pk_fma(sr2[j], wi2[j], si2[j] * wr2[j]);
                sr2[j] = nr; si2[j] = ni;
            }
        }
    }

    // issue FK loads early; latency hides under the lane scan
    const uint4* fgp = (const uint4*)(FKf + (size_t)h * L_ + c * LC_);
    uint4 fk4[8];
    #pragma unroll
    for (int k = 0; k < 8; ++k) fk4[k] = fgp[k];

    // ---- inclusive scan across lanes: S_c = sum_{j<=c} e_j * P^(c-j) ----
    #pragma unroll
    for (int st = 0; st < 6; ++st) {
        int off = 1 << st;
        const float2* mp = (const float2*)(WPp + ((size_t)h * 6 + st) * 64);
        int src  = (c - off) & 63;
        bool act = c >= off;
        #pragma unroll
        for (int j = 0; j < 16; ++j) {
            float pr0 = __shfl(sr2[j].x, src), pr1 = __shfl(sr2[j].y, src);
            float pi0 = __shfl(si2[j].x, src), pi1 = __shfl(si2[j].y, src);
            if (!act) { pr0 = 0.f; pr1 = 0.f; pi0 = 0.f; pi1 = 0.f; }
            f32x2 pr = (f32x2){pr0, pr1};
            f32x2 pi = (f32x2){pi0, pi1};
            float2 mrv = mp[j];                 // Re P^off, d = 2j,2j+1
            float2 miv = mp[16 + j];            // Im P^off
            f32x2 Mr = (f32x2){mrv.x, mrv.y};
            f32x2 Mi = (f32x2){miv.x, miv.y};
            sr2[j] = pk_fma(pr, Mr, pk_fma(-pi, Mi, sr2[j]));
            si2[j] = pk_fma(pr, Mi, pk_fma( pi, Mr, si2[j]));
        }
    }
    // ---- exclusive shift: carry entering chunk c = S_{c-1}; lane 0 -> 0 ----
    {
        int srcm1 = (c - 1) & 63;
        #pragma unroll
        for (int j = 0; j < 16; ++j) {
            float a0 = __shfl(sr2[j].x, srcm1), a1 = __shfl(sr2[j].y, srcm1);
            float b0 = __shfl(si2[j].x, srcm1), b1 = __shfl(si2[j].y, srcm1);
            if (c == 0) { a0 = 0.f; a1 = 0.f; b0 = 0.f; b1 = 0.f; }
            sr2[j] = (f32x2){a0, a1};
            si2[j] = (f32x2){b0, b1};
        }
    }

    // ---- phase B: recurrence from carry, emit outputs ----
    unsigned yw[16];
    float4 un = ((const float4*)ug)[0];         // reload u (L1/L2 hit)
    #pragma unroll
    for (int k = 0; k < 8; ++k) {
        float4 uc = un;
        if (k < 7) un = ((const float4*)ug)[k + 1];
        uint4 f4 = fk4[k];
        float us[4] = {uc.x, uc.y, uc.z, uc.w};
        unsigned fs[4] = {f4.x, f4.y, f4.z, f4.w};
        float g[4];
        #pragma unroll
        for (int e = 0; e < 4; ++e) {
            float2 fk = unpack_bf16x2(fs[e]);
            f32x2 ul2 = (f32x2){us[e], us[e]};
            f32x2 da = (f32x2){0.f, 0.f}, db = (f32x2){0.f, 0.f};
            #pragma unroll
            for (int j = 0; j < 16; ++j) {
                f32x2 nr = pk_fma(sr2[j], wr2[j], pk_fma(-si2[j], wi2[j], ul2));
                f32x2 ni = pk_fma(sr2[j], wi2[j], si2[j] * wr2[j]);
                sr2[j] = nr; si2[j] = ni;
                if (j & 1) db = pk_fma(qs2[j], nr, db);
                else       da = pk_fma(qs2[j], nr, da);
            }
            float dot = (da.x + da.y) + (db.x + db.y);
            float yv = fmaf(c0, us[e], fmaf(c1, fk.x, dot + fk.y));
            g[e] = gelu_exact(yv);
        }
        yw[2 * k]     = pack_bf16x2(g[0], g[1]);
        yw[2 * k + 1] = pack_bf16x2(g[2], g[3]);
    }
    uint4* yp = (uint4*)(y + (size_t)(b * H_ + h) * L_ + c * LC_);
    yp[0] = make_uint4(yw[0],  yw[1],  yw[2],  yw[3]);
    yp[1] = make_uint4(yw[4],  yw[5],  yw[6],  yw[7]);
    yp[2] = make_uint4(yw[8],  yw[9],  yw[10], yw[11]);
    yp[3] = make_uint4(yw[12], yw[13], yw[14], yw[15]);
}

// ---------------- transpose y[b][f][l] -> yT[b][l][f] (bf16) ----------------
__global__ __launch_bounds__(256) void transpose_y_kernel(
        const __hip_bfloat16* __restrict__ y, __hip_bfloat16* __restrict__ yT) {
    __shared__ short tile[64][72];
    int l0 = blockIdx.x * 64, f0 = blockIdx.y * 64, b = blockIdx.z;
    int t = threadIdx.x;
    int row = t >> 3, col8 = (t & 7) * 8;
    const short* yg = (const short*)y + (size_t)b * H_ * L_;
    #pragma unroll
    for (int r2 = 0; r2 < 64; r2 += 32)
        *(uint4*)&tile[row + r2][col8] =
            *(const uint4*)&yg[(size_t)(f0 + row + r2) * L_ + l0 + col8];
    __syncthreads();
    short* og = (short*)yT + (size_t)b * L_ * H_;
    #pragma unroll
    for (int r2 = 0; r2 < 64; r2 += 32) {
        int lrow = row + r2;
        short v[8];
        #pragma unroll
        for (int j = 0; j < 8; ++j) v[j] = tile[col8 + j][lrow];
        *(uint4*)&og[(size_t)(l0 + lrow) * H_ + f0 + col8] = *(uint4*)v;
    }
}

// ---------------- gemm: out[b,h,l] = sum_f W[h,f] * yT[b,l,f] + bias[h] ----------------
__global__ __launch_bounds__(256) void gemm_kernel(
        const __hip_bfloat16* __restrict__ Wb, const __hip_bfloat16* __restrict__ yT,
        const float* __restrict__ bias, float* __restrict__ out) {
    __shared__ __align__(16) short As[128 * 32];
    __shared__ __align__(16) short Bs[128 * 32];
    int l0 = blockIdx.x * 128;
    int h0 = blockIdx.y * 128;
    int b  = blockIdx.z;
    int t    = threadIdx.x;
    int lane = t & 63, wave = t >> 6;
    int m_off = (wave >> 1) * 64, n_off = (wave & 1) * 64;
    int quad = lane >> 4, ln = lane & 15;

    float4v acc[4][4];
    #pragma unroll
    for (int mt = 0; mt < 4; ++mt)
        #pragma unroll
        for (int nt = 0; nt < 4; ++nt)
            acc[mt][nt] = (float4v){0.f, 0.f, 0.f, 0.f};

    const short* Wg = (const short*)Wb;
    const short* Yg = (const short*)(yT + (size_t)b * L_ * H_);

    int r  = t >> 2;
    int qd = t & 3;

    for (int kt = 0; kt < 16; ++kt) {
        int k0 = kt * 32;
        load_lds16(Wg + (h0 + r)      * 512 + k0 + qd * 8, &As[t * 8]);
        load_lds16(Wg + (h0 + r + 64) * 512 + k0 + qd * 8, &As[(t + 256) * 8]);
        load_lds16(Yg + (size_t)(l0 + r)      * 512 + k0 + qd * 8, &Bs[t * 8]);
        load_lds16(Yg + (size_t)(l0 + r + 64) * 512 + k0 + qd * 8, &Bs[(t + 256) * 8]);
        __syncthreads();

        short8 af[4], bf[4];
        #pragma unroll
        for (int mt = 0; mt < 4; ++mt)
            af[mt] = *(const short8*)&As[(m_off + mt * 16 + ln) * 32 + quad * 8];
        #pragma unroll
        for (int nt = 0; nt < 4; ++nt)
            bf[nt] = *(const short8*)&Bs[(n_off + nt * 16 + ln) * 32 + quad * 8];
        #pragma unroll
        for (int mt = 0; mt < 4; ++mt)
            #pragma unroll
            for (int nt = 0; nt < 4; ++nt)
                acc[mt][nt] = __builtin_amdgcn_mfma_f32_16x16x32_bf16(
                    af[mt], bf[nt], acc[mt][nt], 0, 0, 0);
        __syncthreads();
    }

    #pragma unroll
    for (int mt = 0; mt < 4; ++mt) {
        #pragma unroll
        for (int nt = 0; nt < 4; ++nt) {
            int hh = h0 + m_off + mt * 16 + quad * 4;
            int ll = l0 + n_off + nt * 16 + ln;
            #pragma unroll
            for (int r2 = 0; r2 < 4; ++r2)
                out[((size_t)(b * H_ + hh + r2)) * L_ + ll] = acc[mt][nt][r2] + bias[hh + r2];
        }
    }
}

extern "C" void kernel_launch(void* const* d_in, const int* in_sizes, int n_in,
                              void* d_out, int out_size, void* d_ws, size_t ws_size,
                              hipStream_t stream) {
    const float* u    = (const float*)d_in[0];
    const float* a    = (const float*)d_in[1];
    const float* th   = (const float*)d_in[2];
    const float* bb   = (const float*)d_in[3];
    const float* cc   = (const float*)d_in[4];
    const float* x0   = (const float*)d_in[5];
    const float* Dp   = (const float*)d_in[6];
    const float* W    = (const float*)d_in[7];
    const float* bias = (const float*)d_in[8];
    float* out = (float*)d_out;
    char* ws = (char*)d_ws;

    // layout: FKf 4M @0 | yT 16M @4M | y 16M @36M | Wb 0.5M @52M | params @52.5M
    // (E buffer + combine pass eliminated: carry scan is now in-wave via shfl.)
    // params: 7 x 64KB arrays, then WP (H*6*64 f32 = 768KB). ws_size >= 57 MiB proven in R3.
    unsigned*       FKf = (unsigned*)ws;
    __hip_bfloat16* yT  = (__hip_bfloat16*)(ws + (4ull  << 20));
    __hip_bfloat16* y   = (__hip_bfloat16*)(ws + (36ull << 20));
    __hip_bfloat16* Wb  = (__hip_bfloat16*)(ws + (52ull << 20));
    float* pbase = (float*)(ws + (52ull << 20) + (512ull << 10));
    float *aT  = pbase,            *thT = pbase + 16384,   *qT  = pbase + 2*16384,
          *gxT = pbase + 3*16384,  *WRh = pbase + 4*16384, *WIh = pbase + 5*16384,
          *QSh = pbase + 6*16384,  *WPp = pbase + 7*16384;

    hipLaunchKernelGGL(cast_prep_kernel,  dim3(1024),      dim3(256), 0, stream,
                       W, Wb, a, th, bb, cc, x0, aT, thT, qT, gxT, WRh, WIh, QSh, WPp);
    hipLaunchKernelGGL(fk_kernel,         dim3(L_/LCF, 8), dim3(256), 0, stream,
                       aT, thT, qT, gxT, FKf);
    hipLaunchKernelGGL(scan_fused_kernel, dim3(H_/2, B_),  dim3(128), 0, stream,
                       u, WRh, WIh, QSh, WPp, Dp, FKf, y);
    hipLaunchKernelGGL(transpose_y_kernel,dim3(32, 8, 8),  dim3(256), 0, stream, y, yT);
    hipLaunchKernelGGL(gemm_kernel,       dim3(16, 4, 8),  dim3(256), 0, stream,
                       Wb, yT, bias, out);
}

// Round 2
// 191.757 us; speedup vs baseline: 1.1486x; 1.1486x over previous
//
#include <hip/hip_runtime.h>
#include <hip/hip_bf16.h>

#define B_  8
#define H_  512
#define L_  2048
#define D2_ 32
#define NC_ 64
#define LC_ 32    // L_/NC_
#define LCF 32    // fk kernel l-chunk
#define EP  36    // E_lds row pitch in u32 (16B-aligned rows)

typedef __attribute__((ext_vector_type(8))) short short8;   // 8 bf16 (4 VGPRs)
typedef __attribute__((ext_vector_type(4))) float float4v;  // 4 fp32 acc
typedef __attribute__((ext_vector_type(2))) float f32x2;    // packed fp32 (v_pk_*)

__device__ __forceinline__ f32x2 pk_fma(f32x2 a, f32x2 b, f32x2 c) {
    return __builtin_elementwise_fma(a, b, c);
}

__device__ __forceinline__ float gelu_exact(float x) {
    return 0.5f * x * (1.0f + erff(x * 0.70710678118654752f));
}

__device__ __forceinline__ unsigned pack_bf16x2(float x, float y) {
    __hip_bfloat162 p = __float22bfloat162_rn(make_float2(x, y));
    return *(unsigned*)&p;
}
__device__ __forceinline__ float2 unpack_bf16x2(unsigned v) {
    __hip_bfloat162 p = *(__hip_bfloat162*)&v;
    return __bfloat1622float2(p);
}

__device__ __forceinline__ void load_lds16(const void* g, void* l) {
    __builtin_amdgcn_global_load_lds((const __attribute__((address_space(1))) unsigned int*)g,
                                     (__attribute__((address_space(3))) unsigned int*)l, 16, 0, 0);
}

// ---------------- cast W -> bf16, fused param prep ----------------
// WPp: per-h chunk-combine multipliers P^(2^k), P = w^32, k = 0..5.
__global__ void cast_prep_kernel(const float* __restrict__ W, __hip_bfloat16* __restrict__ Wb,
                                 const float* __restrict__ a, const float* __restrict__ th,
                                 const float* __restrict__ bb, const float* __restrict__ cc,
                                 const float* __restrict__ x0,
                                 float* __restrict__ aT, float* __restrict__ thT,
                                 float* __restrict__ qT, float* __restrict__ gxT,
                                 float* __restrict__ WPp) {
    int tid = blockIdx.x * 256 + threadIdx.x;   // 262144
    Wb[tid] = __float2bfloat16(W[tid]);
    if (tid < H_ * D2_) {                        // tid = d*H + h (d-major)
        int h = tid & (H_ - 1);
        int d = tid >> 9;
        const float T = 1.0f / (float)(L_ - 1);
        float av = -fabsf(a[h * D2_ + d]);
        float tv = th[h * D2_ + d];
        float q  = bb[h * D2_ + d] * cc[h * D2_ + d];
        aT[tid]  = av;
        thT[tid] = tv;
        qT[tid]  = q;
        gxT[tid] = 2.0f * cc[h * D2_ + d] * x0[h * D2_ + d];
        #pragma unroll
        for (int k = 0; k < 6; ++k) {
            float len = (float)(32 << k);        // 32 * 2^k steps
            float e2  = __expf(av * T * len);
            float an  = tv * T * len;
            WPp[((size_t)h * 6 + k) * 64 + d]      = e2 * __cosf(an);
            WPp[((size_t)h * 6 + k) * 64 + 32 + d] = e2 * __sinf(an);
        }
    }
}

// ---------------- fk: FKf[h*L + l] = bf16x2{ f[h,l], k0[h,l] } ----------------
__global__ __launch_bounds__(256) void fk_kernel(
        const float* __restrict__ aT, const float* __restrict__ thT,
        const float* __restrict__ qT, const float* __restrict__ gxT,
        unsigned* __restrict__ FKf) {
    int t = threadIdx.x;
    int q4 = t & 3, hl = t >> 2;
    int h  = blockIdx.y * 64 + hl;
    int l0 = blockIdx.x * LCF;
    const float T = 1.0f / (float)(L_ - 1);
    float z0 = T * (float)l0;
    float pr[8], pi[8], wr[8], wi[8], qd[8], gx[8];
    #pragma unroll
    for (int j = 0; j < 8; ++j) {
        int idx = (q4 * 8 + j) * H_ + h;
        float aa = aT[idx], tv = thT[idx];
        float e0 = __expf(aa * z0);
        pr[j] = e0 * __cosf(tv * z0);
        pi[j] = e0 * __sinf(tv * z0);
        float e1 = __expf(aa * T);
        wr[j] = e1 * __cosf(tv * T);
        wi[j] = e1 * __sinf(tv * T);
        qd[j] = qT[idx];
        gx[j] = gxT[idx];
    }
    for (int i = 0; i < LCF; ++i) {
        float fa = 0.f, ka = 0.f;
        #pragma unroll
        for (int j = 0; j < 8; ++j) {
            fa = fmaf(qd[j], pr[j], fa);
            ka = fmaf(gx[j], pr[j], ka);
            float nr = fmaf(pr[j], wr[j], -(pi[j] * wi[j]));
            float ni = fmaf(pr[j], wi[j],  (pi[j] * wr[j]));
            pr[j] = nr; pi[j] = ni;
        }
        fa += __shfl_xor(fa, 1); fa += __shfl_xor(fa, 2);
        ka += __shfl_xor(ka, 1); ka += __shfl_xor(ka, 2);
        if (q4 == 0)
            FKf[(size_t)h * L_ + l0 + i] = pack_bf16x2(2.0f * T * fa, ka);
    }
}

// ---------------- prep2: build MFMA operand matrices per h ----------------
// AB[h][m][i] (64x32 bf16): m<32: Re(W_d^{31-i}) d=m; m>=32: Im(W_d^{31-i}) d=m-32.
// CB[h][i][k] (32x96 bf16): k<32: Toeplitz f[i-k] (k<=i, else 0);
//                           k in [32,64): d=k-32:  qs_d*Re(W_d^{i+1});
//                           k in [64,96): d=k-64: -qs_d*Im(W_d^{i+1}).
__global__ __launch_bounds__(256) void prep2_kernel(
        const float* __restrict__ aT, const float* __restrict__ thT,
        const float* __restrict__ qT, const unsigned* __restrict__ FKf,
        __hip_bfloat16* __restrict__ AB, __hip_bfloat16* __restrict__ CB) {
    int h = blockIdx.x;
    int t = threadIdx.x;
    const float T = 1.0f / (float)(L_ - 1);
    for (int e = t; e < 64 * 32; e += 256) {
        int m = e >> 5, i = e & 31;
        int d = m & 31;
        float av = aT[d * H_ + h], tv = thT[d * H_ + h];
        float z  = T * (float)(31 - i);
        float ex = __expf(av * z);
        float v  = (m < 32) ? ex * __cosf(tv * z) : ex * __sinf(tv * z);
        AB[(size_t)h * 2048 + e] = __float2bfloat16(v);
    }
    unsigned short* CBs = (unsigned short*)CB;
    for (int e = t; e < 32 * 96; e += 256) {
        int i = e / 96, k = e - i * 96;
        if (k < 32) {
            unsigned short bits = 0;
            if (k <= i) bits = (unsigned short)(FKf[(size_t)h * L_ + (i - k)] & 0xFFFFu);
            CBs[(size_t)h * 3072 + e] = bits;      // raw bf16 bits of f[i-k]
        } else {
            int d = (k < 64) ? k - 32 : k - 64;
            float av = aT[d * H_ + h], tv = thT[d * H_ + h];
            float qs = 2.0f * T * qT[d * H_ + h];
            float z  = T * (float)(i + 1);
            float ex = __expf(av * z);
            float v  = (k < 64) ? qs * ex * __cosf(tv * z) : -qs * ex * __sinf(tv * z);
            CB[(size_t)h * 3072 + e] = __float2bfloat16(v);
        }
    }
}

// ---------------- scan_mfma: chunked SSD-style scan on matrix cores ----------------
// Per wave = one (b,h):
//   M1: [Ar;Ai](64x32) @ U(32x64) -> E (chunk end-states)  [MFMA]
//   Hillis-Steele shfl scan over 64 chunks (verified R1 code) -> carries S_in
//   M2: [T_f|Qr|-Qi](32x96) @ [U;Sr;Si](96x64) -> y_pre     [MFMA]
//   epilogue: + c0*u + c1*f + k0, gelu, pack bf16.
__global__ __launch_bounds__(128) void scan_mfma_kernel(
        const float* __restrict__ u, const __hip_bfloat16* __restrict__ AB,
        const __hip_bfloat16* __restrict__ CB, const float* __restrict__ WPp,
        const float* __restrict__ Dp, const unsigned* __restrict__ FKf,
        __hip_bfloat16* __restrict__ y) {
    __shared__ unsigned E_lds[2][64 * EP];
    int wid = threadIdx.x >> 6, lane = threadIdx.x & 63;
    int h = blockIdx.x * 2 + wid, b = blockIdx.y;
    int ln = lane & 15, qq = lane >> 4;
    unsigned* El = E_lds[wid];
    const float* ug = u + (size_t)(b * H_ + h) * L_;

    // ---- U fragments (B-operand, tile nb: col c = nb*16+ln, k=i = qq*8+j) ----
    short8 uf[4];
    #pragma unroll
    for (int nb = 0; nb < 4; ++nb) {
        const float* p = ug + (nb * 16 + ln) * 32 + qq * 8;
        float4 a0 = *(const float4*)p;
        float4 a1 = *(const float4*)(p + 4);
        short8 v;
        ((unsigned*)&v)[0] = pack_bf16x2(a0.x, a0.y);
        ((unsigned*)&v)[1] = pack_bf16x2(a0.z, a0.w);
        ((unsigned*)&v)[2] = pack_bf16x2(a1.x, a1.y);
        ((unsigned*)&v)[3] = pack_bf16x2(a1.z, a1.w);
        uf[nb] = v;
    }

    // ---- M1: E = [Ar;Ai] @ U, two halves (Er then Ei) ----
    const short* ABh = (const short*)AB + (size_t)h * 64 * 32;
    #pragma unroll
    for (int e = 0; e < 2; ++e) {
        short8 af[2];
        #pragma unroll
        for (int mb = 0; mb < 2; ++mb)
            af[mb] = *(const short8*)&ABh[(e * 32 + mb * 16 + ln) * 32 + qq * 8];
        float4v acc[2][4];
        #pragma unroll
        for (int mb = 0; mb < 2; ++mb)
            #pragma unroll
            for (int nb = 0; nb < 4; ++nb)
                acc[mb][nb] = (float4v){0.f, 0.f, 0.f, 0.f};
        #pragma unroll
        for (int mb = 0; mb < 2; ++mb)
            #pragma unroll
            for (int nb = 0; nb < 4; ++nb)
                acc[mb][nb] = __builtin_amdgcn_mfma_f32_16x16x32_bf16(
                    af[mb], uf[nb], acc[mb][nb], 0, 0, 0);
        // store E to LDS, packed bf16 pairs: row c, u32 idx m/2 (Er: 0..15, Ei: 16..31)
        #pragma unroll
        for (int mb = 0; mb < 2; ++mb)
            #pragma unroll
            for (int nb = 0; nb < 4; ++nb) {
                int m2 = e * 16 + mb * 8 + qq * 2;
                unsigned p0 = pack_bf16x2(acc[mb][nb][0], acc[mb][nb][1]);
                unsigned p1 = pack_bf16x2(acc[mb][nb][2], acc[mb][nb][3]);
                *(uint2*)&El[(nb * 16 + ln) * EP + m2] = make_uint2(p0, p1);
            }
    }
    __syncthreads();

    // ---- scan over chunks, lane = c (verified R1 Hillis-Steele) ----
    int c = lane;
    f32x2 sr2[16], si2[16];
    #pragma unroll
    for (int jj = 0; jj < 4; ++jj) {
        uint4 er = *(const uint4*)&El[c * EP + jj * 4];
        uint4 ei = *(const uint4*)&El[c * EP + 16 + jj * 4];
        unsigned ers[4] = {er.x, er.y, er.z, er.w};
        unsigned eis[4] = {ei.x, ei.y, ei.z, ei.w};
        #pragma unroll
        for (int w = 0; w < 4; ++w) {
            float2 pr = unpack_bf16x2(ers[w]);
            float2 pi = unpack_bf16x2(eis[w]);
            sr2[jj * 4 + w] = (f32x2){pr.x, pr.y};
            si2[jj * 4 + w] = (f32x2){pi.x, pi.y};
        }
    }
    #pragma unroll
    for (int st = 0; st < 6; ++st) {
        int off = 1 << st;
        const float2* mp = (const float2*)(WPp + ((size_t)h * 6 + st) * 64);
        int src  = (c - off) & 63;
        bool act = c >= off;
        #pragma unroll
        for (int j = 0; j < 16; ++j) {
            float pr0 = __shfl(sr2[j].x, src), pr1 = __shfl(sr2[j].y, src);
            float pi0 = __shfl(si2[j].x, src), pi1 = __shfl(si2[j].y, src);
            if (!act) { pr0 = 0.f; pr1 = 0.f; pi0 = 0.f; pi1 = 0.f; }
            f32x2 pr = (f32x2){pr0, pr1};
            f32x2 pi = (f32x2){pi0, pi1};
            float2 mrv = mp[j];
            float2 miv = mp[16 + j];
            f32x2 Mr = (f32x2){mrv.x, mrv.y};
            f32x2 Mi = (f32x2){miv.x, miv.y};
            sr2[j] = pk_fma(pr, Mr, pk_fma(-pi, Mi, sr2[j]));
            si2[j] = pk_fma(pr, Mi, pk_fma( pi, Mr, si2[j]));
        }
    }
    {   // exclusive shift: carry entering chunk c = S_{c-1}; lane 0 -> 0
        int srcm1 = (c - 1) & 63;
        #pragma unroll
        for (int j = 0; j < 16; ++j) {
            float a0 = __shfl(sr2[j].x, srcm1), a1 = __shfl(sr2[j].y, srcm1);
            float b0 = __shfl(si2[j].x, srcm1), b1 = __shfl(si2[j].y, srcm1);
            if (c == 0) { a0 = 0.f; a1 = 0.f; b0 = 0.f; b1 = 0.f; }
            sr2[j] = (f32x2){a0, a1};
            si2[j] = (f32x2){b0, b1};
        }
    }
    // pack carries back to LDS: row c, Sr pairs at [0..15], Si at [16..31]
    #pragma unroll
    for (int jj = 0; jj < 4; ++jj) {
        uint4 pr, pi;
        pr.x = pack_bf16x2(sr2[jj*4+0].x, sr2[jj*4+0].y);
        pr.y = pack_bf16x2(sr2[jj*4+1].x, sr2[jj*4+1].y);
        pr.z = pack_bf16x2(sr2[jj*4+2].x, sr2[jj*4+2].y);
        pr.w = pack_bf16x2(sr2[jj*4+3].x, sr2[jj*4+3].y);
        pi.x = pack_bf16x2(si2[jj*4+0].x, si2[jj*4+0].y);
        pi.y = pack_bf16x2(si2[jj*4+1].x, si2[jj*4+1].y);
        pi.z = pack_bf16x2(si2[jj*4+2].x, si2[jj*4+2].y);
        pi.w = pack_bf16x2(si2[jj*4+3].x, si2[jj*4+3].y);
        *(uint4*)&El[c * EP + jj * 4] = pr;
        *(uint4*)&El[c * EP + 16 + jj * 4] = pi;
    }
    __syncthreads();

    // ---- M2: y_pre = [T_f | Qr | -Qi] @ [U; Sr; Si] ----
    const short* CBh = (const short*)CB + (size_t)h * 32 * 96;
    float4v acc2[2][4];
    #pragma unroll
    for (int mb = 0; mb < 2; ++mb)
        #pragma unroll
        for (int nb = 0; nb < 4; ++nb)
            acc2[mb][nb] = (float4v){0.f, 0.f, 0.f, 0.f};
    #pragma unroll
    for (int ks = 0; ks < 3; ++ks) {
        short8 a2[2];
        #pragma unroll
        for (int mb = 0; mb < 2; ++mb)
            a2[mb] = *(const short8*)&CBh[(mb * 16 + ln) * 96 + ks * 32 + qq * 8];
        short8 bf_[4];
        if (ks == 0) {
            #pragma unroll
            for (int nb = 0; nb < 4; ++nb) bf_[nb] = uf[nb];
        } else {
            int off = (ks == 1) ? 0 : 16;
            #pragma unroll
            for (int nb = 0; nb < 4; ++nb)
                bf_[nb] = *(const short8*)&El[(nb * 16 + ln) * EP + off + qq * 4];
        }
        #pragma unroll
        for (int mb = 0; mb < 2; ++mb)
            #pragma unroll
            for (int nb = 0; nb < 4; ++nb)
                acc2[mb][nb] = __builtin_amdgcn_mfma_f32_16x16x32_bf16(
                    a2[mb], bf_[nb], acc2[mb][nb], 0, 0, 0);
    }

    // ---- epilogue: y = y_pre + c0*u + c1*f + k0, gelu, pack ----
    float f0; { float2 t0 = unpack_bf16x2(FKf[(size_t)h * L_]); f0 = t0.x; }
    float c0v = Dp[h] - 0.5f * f0;
    float u0  = ug[0];
    float c1v = -0.5f * u0;
    #pragma unroll
    for (int mb = 0; mb < 2; ++mb)
        #pragma unroll
        for (int nb = 0; nb < 4; ++nb) {
            int l0 = (nb * 16 + ln) * 32 + mb * 16 + qq * 4;
            float4 u4 = *(const float4*)(ug + l0);
            uint4 fkv = *(const uint4*)(FKf + (size_t)h * L_ + l0);
            float us[4] = {u4.x, u4.y, u4.z, u4.w};
            unsigned fs[4] = {fkv.x, fkv.y, fkv.z, fkv.w};
            float g[4];
            #pragma unroll
            for (int r = 0; r < 4; ++r) {
                float2 fk = unpack_bf16x2(fs[r]);
                float yv = acc2[mb][nb][r] + fmaf(c0v, us[r], fmaf(c1v, fk.x, fk.y));
                g[r] = gelu_exact(yv);
            }
            uint2 yo;
            yo.x = pack_bf16x2(g[0], g[1]);
            yo.y = pack_bf16x2(g[2], g[3]);
            *(uint2*)((short*)y + (size_t)(b * H_ + h) * L_ + l0) = yo;
        }
}

// ---------------- transpose y[b][f][l] -> yT[b][l][f] (bf16) ----------------
__global__ __launch_bounds__(256) void transpose_y_kernel(
        const __hip_bfloat16* __restrict__ y, __hip_bfloat16* __restrict__ yT) {
    __shared__ short tile[64][72];
    int l0 = blockIdx.x * 64, f0 = blockIdx.y * 64, b = blockIdx.z;
    int t = threadIdx.x;
    int row = t >> 3, col8 = (t & 7) * 8;
    const short* yg = (const short*)y + (size_t)b * H_ * L_;
    #pragma unroll
    for (int r2 = 0; r2 < 64; r2 += 32)
        *(uint4*)&tile[row + r2][col8] =
            *(const uint4*)&yg[(size_t)(f0 + row + r2) * L_ + l0 + col8];
    __syncthreads();
    short* og = (short*)yT + (size_t)b * L_ * H_;
    #pragma unroll
    for (int r2 = 0; r2 < 64; r2 += 32) {
        int lrow = row + r2;
        short v[8];
        #pragma unroll
        for (int j = 0; j < 8; ++j) v[j] = tile[col8 + j][lrow];
        *(uint4*)&og[(size_t)(l0 + lrow) * H_ + f0 + col8] = *(uint4*)v;
    }
}

// ---------------- gemm: out[b,h,l] = sum_f W[h,f] * yT[b,l,f] + bias[h] ----------------
__global__ __launch_bounds__(256) void gemm_kernel(
        const __hip_bfloat16* __restrict__ Wb, const __hip_bfloat16* __restrict__ yT,
        const float* __restrict__ bias, float* __restrict__ out) {
    __shared__ __align__(16) short As[128 * 32];
    __shared__ __align__(16) short Bs[128 * 32];
    int l0 = blockIdx.x * 128;
    int h0 = blockIdx.y * 128;
    int b  = blockIdx.z;
    int t    = threadIdx.x;
    int lane = t & 63, wave = t >> 6;
    int m_off = (wave >> 1) * 64, n_off = (wave & 1) * 64;
    int quad = lane >> 4, ln = lane & 15;

    float4v acc[4][4];
    #pragma unroll
    for (int mt = 0; mt < 4; ++mt)
        #pragma unroll
        for (int nt = 0; nt < 4; ++nt)
            acc[mt][nt] = (float4v){0.f, 0.f, 0.f, 0.f};

    const short* Wg = (const short*)Wb;
    const short* Yg = (const short*)(yT + (size_t)b * L_ * H_);

    int r  = t >> 2;
    int qd = t & 3;

    for (int kt = 0; kt < 16; ++kt) {
        int k0 = kt * 32;
        load_lds16(Wg + (h0 + r)      * 512 + k0 + qd * 8, &As[t * 8]);
        load_lds16(Wg + (h0 + r + 64) * 512 + k0 + qd * 8, &As[(t + 256) * 8]);
        load_lds16(Yg + (size_t)(l0 + r)      * 512 + k0 + qd * 8, &Bs[t * 8]);
        load_lds16(Yg + (size_t)(l0 + r + 64) * 512 + k0 + qd * 8, &Bs[(t + 256) * 8]);
        __syncthreads();

        short8 af[4], bf[4];
        #pragma unroll
        for (int mt = 0; mt < 4; ++mt)
            af[mt] = *(const short8*)&As[(m_off + mt * 16 + ln) * 32 + quad * 8];
        #pragma unroll
        for (int nt = 0; nt < 4; ++nt)
            bf[nt] = *(const short8*)&Bs[(n_off + nt * 16 + ln) * 32 + quad * 8];
        #pragma unroll
        for (int mt = 0; mt < 4; ++mt)
            #pragma unroll
            for (int nt = 0; nt < 4; ++nt)
                acc[mt][nt] = __builtin_amdgcn_mfma_f32_16x16x32_bf16(
                    af[mt], bf[nt], acc[mt][nt], 0, 0, 0);
        __syncthreads();
    }

    #pragma unroll
    for (int mt = 0; mt < 4; ++mt) {
        #pragma unroll
        for (int nt = 0; nt < 4; ++nt) {
            int hh = h0 + m_off + mt * 16 + quad * 4;
            int ll = l0 + n_off + nt * 16 + ln;
            #pragma unroll
            for (int r2 = 0; r2 < 4; ++r2)
                out[((size_t)(b * H_ + hh + r2)) * L_ + ll] = acc[mt][nt][r2] + bias[hh + r2];
        }
    }
}

extern "C" void kernel_launch(void* const* d_in, const int* in_sizes, int n_in,
                              void* d_out, int out_size, void* d_ws, size_t ws_size,
                              hipStream_t stream) {
    const float* u    = (const float*)d_in[0];
    const float* a    = (const float*)d_in[1];
    const float* th   = (const float*)d_in[2];
    const float* bb   = (const float*)d_in[3];
    const float* cc   = (const float*)d_in[4];
    const float* x0   = (const float*)d_in[5];
    const float* Dp   = (const float*)d_in[6];
    const float* W    = (const float*)d_in[7];
    const float* bias = (const float*)d_in[8];
    float* out = (float*)d_out;
    char* ws = (char*)d_ws;

    // layout (compact, no aliasing):
    // FKf 4M @0 | yT 16M @4M | y 16M @20M | Wb 0.5M @36M | AB 2M @37M | CB 3M @39M
    // params @42M: aT,thT,qT,gxT (4x64KB) then WPp (768KB) -> ends ~43.1M
    unsigned*       FKf = (unsigned*)ws;
    __hip_bfloat16* yT  = (__hip_bfloat16*)(ws + (4ull  << 20));
    __hip_bfloat16* y   = (__hip_bfloat16*)(ws + (20ull << 20));
    __hip_bfloat16* Wb  = (__hip_bfloat16*)(ws + (36ull << 20));
    __hip_bfloat16* AB  = (__hip_bfloat16*)(ws + (37ull << 20));
    __hip_bfloat16* CB  = (__hip_bfloat16*)(ws + (39ull << 20));
    float* pbase = (float*)(ws + (42ull << 20));
    float *aT  = pbase,           *thT = pbase + 16384, *qT = pbase + 2*16384,
          *gxT = pbase + 3*16384, *WPp = pbase + 4*16384;

    hipLaunchKernelGGL(cast_prep_kernel,  dim3(1024),      dim3(256), 0, stream,
                       W, Wb, a, th, bb, cc, x0, aT, thT, qT, gxT, WPp);
    hipLaunchKernelGGL(fk_kernel,         dim3(L_/LCF, 8), dim3(256), 0, stream,
                       aT, thT, qT, gxT, FKf);
    hipLaunchKernelGGL(prep2_kernel,      dim3(H_),        dim3(256), 0, stream,
                       aT, thT, qT, FKf, AB, CB);
    hipLaunchKernelGGL(scan_mfma_kernel,  dim3(H_/2, B_),  dim3(128), 0, stream,
                       u, AB, CB, WPp, Dp, FKf, y);
    hipLaunchKernelGGL(transpose_y_kernel,dim3(32, 8, 8),  dim3(256), 0, stream, y, yT);
    hipLaunchKernelGGL(gemm_kernel,       dim3(16, 4, 8),  dim3(256), 0, stream,
                       Wb, yT, bias, out);
}

// Round 3
// 177.825 us; speedup vs baseline: 1.2386x; 1.0783x over previous
//
#include <hip/hip_runtime.h>
#include <hip/hip_bf16.h>

#define B_  8
#define H_  512
#define L_  2048
#define D2_ 32
#define NC_ 64
#define LC_ 32    // L_/NC_
#define LCF 32    // fk kernel l-chunk
#define EP  36    // E_lds row pitch in u32 (16B-aligned rows)

typedef __attribute__((ext_vector_type(8))) short short8;     // 8 bf16 (4 VGPRs)
typedef __attribute__((ext_vector_type(8))) _Float16 half8;   // 8 fp16 (4 VGPRs)
typedef __attribute__((ext_vector_type(2))) _Float16 half2v;  // packed fp16 (v_pk_*)
typedef __attribute__((ext_vector_type(4))) float float4v;    // 4 fp32 acc

__device__ __forceinline__ half2v pk_fma16(half2v a, half2v b, half2v c) {
    return __builtin_elementwise_fma(a, b, c);
}

// tanh-form GELU: max |err| vs exact ~3e-4, far below bf16 y-storage ulp.
__device__ __forceinline__ float gelu_fast(float x) {
    float q = x * fmaf(0.044715f, x * x, 1.0f);
    float s = __expf(-1.5957691216057308f * q);   // e^{-2*0.79788456*q}
    return __fdividef(x, 1.0f + s);               // x * sigmoid(2w)
}

__device__ __forceinline__ unsigned pack_bf16x2(float x, float y) {
    __hip_bfloat162 p = __float22bfloat162_rn(make_float2(x, y));
    return *(unsigned*)&p;
}
__device__ __forceinline__ float2 unpack_bf16x2(unsigned v) {
    __hip_bfloat162 p = *(__hip_bfloat162*)&v;
    return __bfloat1622float2(p);
}
__device__ __forceinline__ unsigned pack_f16x2(float x, float y) {
    auto v = __builtin_amdgcn_cvt_pkrtz(x, y);    // v_cvt_pkrtz_f16_f32
    return *(unsigned*)&v;
}

__device__ __forceinline__ void load_lds16(const void* g, void* l) {
    __builtin_amdgcn_global_load_lds((const __attribute__((address_space(1))) unsigned int*)g,
                                     (__attribute__((address_space(3))) unsigned int*)l, 16, 0, 0);
}

// ---------------- cast W -> bf16, fused param prep ----------------
// WPh (fp16): per-h chunk-combine multipliers P^(2^k), P = w^32, k=0..5.
// u32 view: [(h*6+k)*32 + j] = {Mr_2j, Mr_2j+1}; [+16+j] = {Mi_2j, Mi_2j+1}.
__global__ void cast_prep_kernel(const float* __restrict__ W, __hip_bfloat16* __restrict__ Wb,
                                 const float* __restrict__ a, const float* __restrict__ th,
                                 const float* __restrict__ bb, const float* __restrict__ cc,
                                 const float* __restrict__ x0,
                                 float* __restrict__ aT, float* __restrict__ thT,
                                 float* __restrict__ qT, float* __restrict__ gxT,
                                 _Float16* __restrict__ WPh) {
    int tid = blockIdx.x * 256 + threadIdx.x;   // 262144
    Wb[tid] = __float2bfloat16(W[tid]);
    if (tid < H_ * D2_) {                        // tid = d*H + h (d-major)
        int h = tid & (H_ - 1);
        int d = tid >> 9;
        const float T = 1.0f / (float)(L_ - 1);
        float av = -fabsf(a[h * D2_ + d]);
        float tv = th[h * D2_ + d];
        float q  = bb[h * D2_ + d] * cc[h * D2_ + d];
        aT[tid]  = av;
        thT[tid] = tv;
        qT[tid]  = q;
        gxT[tid] = 2.0f * cc[h * D2_ + d] * x0[h * D2_ + d];
        #pragma unroll
        for (int k = 0; k < 6; ++k) {
            float len = (float)(32 << k);        // 32 * 2^k steps
            float e2  = __expf(av * T * len);
            float an  = tv * T * len;
            WPh[((size_t)h * 6 + k) * 64 + d]      = (_Float16)(e2 * __cosf(an));
            WPh[((size_t)h * 6 + k) * 64 + 32 + d] = (_Float16)(e2 * __sinf(an));
        }
    }
}

// ---------------- fk: FKf[h*L + l] = bf16x2{ f[h,l], k0[h,l] } ----------------
__global__ __launch_bounds__(256) void fk_kernel(
        const float* __restrict__ aT, const float* __restrict__ thT,
        const float* __restrict__ qT, const float* __restrict__ gxT,
        unsigned* __restrict__ FKf) {
    int t = threadIdx.x;
    int q4 = t & 3, hl = t >> 2;
    int h  = blockIdx.y * 64 + hl;
    int l0 = blockIdx.x * LCF;
    const float T = 1.0f / (float)(L_ - 1);
    float z0 = T * (float)l0;
    float pr[8], pi[8], wr[8], wi[8], qd[8], gx[8];
    #pragma unroll
    for (int j = 0; j < 8; ++j) {
        int idx = (q4 * 8 + j) * H_ + h;
        float aa = aT[idx], tv = thT[idx];
        float e0 = __expf(aa * z0);
        pr[j] = e0 * __cosf(tv * z0);
        pi[j] = e0 * __sinf(tv * z0);
        float e1 = __expf(aa * T);
        wr[j] = e1 * __cosf(tv * T);
        wi[j] = e1 * __sinf(tv * T);
        qd[j] = qT[idx];
        gx[j] = gxT[idx];
    }
    for (int i = 0; i < LCF; ++i) {
        float fa = 0.f, ka = 0.f;
        #pragma unroll
        for (int j = 0; j < 8; ++j) {
            fa = fmaf(qd[j], pr[j], fa);
            ka = fmaf(gx[j], pr[j], ka);
            float nr = fmaf(pr[j], wr[j], -(pi[j] * wi[j]));
            float ni = fmaf(pr[j], wi[j],  (pi[j] * wr[j]));
            pr[j] = nr; pi[j] = ni;
        }
        fa += __shfl_xor(fa, 1); fa += __shfl_xor(fa, 2);
        ka += __shfl_xor(ka, 1); ka += __shfl_xor(ka, 2);
        if (q4 == 0)
            FKf[(size_t)h * L_ + l0 + i] = pack_bf16x2(2.0f * T * fa, ka);
    }
}

// ---------------- prep2: build MFMA operand matrices per h (fp16) ----------------
// AB[h][m][i] (64x32): m<32: Re(W_d^{31-i}) d=m; m>=32: Im(W_d^{31-i}).
// CB[h][i][k] (32x96): k<32: Toeplitz f[i-k] (k<=i else 0);
//                      k in [32,64): d=k-32:  qs_d*Re(W_d^{i+1});
//                      k in [64,96): d=k-64: -qs_d*Im(W_d^{i+1}).
__global__ __launch_bounds__(256) void prep2_kernel(
        const float* __restrict__ aT, const float* __restrict__ thT,
        const float* __restrict__ qT, const unsigned* __restrict__ FKf,
        _Float16* __restrict__ AB, _Float16* __restrict__ CB) {
    int h = blockIdx.x;
    int t = threadIdx.x;
    const float T = 1.0f / (float)(L_ - 1);
    for (int e = t; e < 64 * 32; e += 256) {
        int m = e >> 5, i = e & 31;
        int d = m & 31;
        float av = aT[d * H_ + h], tv = thT[d * H_ + h];
        float z  = T * (float)(31 - i);
        float ex = __expf(av * z);
        float v  = (m < 32) ? ex * __cosf(tv * z) : ex * __sinf(tv * z);
        AB[(size_t)h * 2048 + e] = (_Float16)v;
    }
    for (int e = t; e < 32 * 96; e += 256) {
        int i = e / 96, k = e - i * 96;
        float v = 0.f;
        if (k < 32) {
            if (k <= i) {
                unsigned fw = FKf[(size_t)h * L_ + (i - k)];
                v = unpack_bf16x2(fw).x;
            }
        } else {
            int d = (k < 64) ? k - 32 : k - 64;
            float av = aT[d * H_ + h], tv = thT[d * H_ + h];
            float qs = 2.0f * T * qT[d * H_ + h];
            float z  = T * (float)(i + 1);
            float ex = __expf(av * z);
            v = (k < 64) ? qs * ex * __cosf(tv * z) : -qs * ex * __sinf(tv * z);
        }
        CB[(size_t)h * 3072 + e] = (_Float16)v;
    }
}

// ---------------- scan_mfma v2: 2 waves per (b,h), fp16 MFMA + packed-fp16 scan ----
// Wave wid owns d in [wid*16, wid*16+16)  (pairs j in [wid*8, wid*8+8)):
//   M1 (8 mfma f16): its Er/Ei rows -> El (fp16x2 pairs)
//   lgkmcnt(0) (own-wave data only, no barrier needed)
//   packed-fp16 Hillis-Steele over 64 chunks (1 shfl per pair) -> carries
//   single __syncthreads
//   M2 (12 mfma f16): its 2 column-tiles; epilogue: its 32 columns.
__global__ __launch_bounds__(128, 6) void scan_mfma_kernel(
        const float* __restrict__ u, const _Float16* __restrict__ AB,
        const _Float16* __restrict__ CB, const unsigned* __restrict__ WPh,
        const float* __restrict__ Dp, const unsigned* __restrict__ FKf,
        __hip_bfloat16* __restrict__ y) {
    __shared__ __align__(16) unsigned El[64 * EP];
    int wid = threadIdx.x >> 6, lane = threadIdx.x & 63;
    int h = blockIdx.x, b = blockIdx.y;
    int ln = lane & 15, qq = lane >> 4;
    const float* ug = u + (size_t)(b * H_ + h) * L_;

    // ---- U fragments (fp16), all 4 column-tiles (needed as M1 B-operand) ----
    half8 uf[4];
    #pragma unroll
    for (int nb = 0; nb < 4; ++nb) {
        const float* p = ug + (nb * 16 + ln) * 32 + qq * 8;
        float4 a0 = *(const float4*)p;
        float4 a1 = *(const float4*)(p + 4);
        unsigned* vp = (unsigned*)&uf[nb];
        vp[0] = pack_f16x2(a0.x, a0.y);
        vp[1] = pack_f16x2(a0.z, a0.w);
        vp[2] = pack_f16x2(a1.x, a1.y);
        vp[3] = pack_f16x2(a1.z, a1.w);
    }

    // ---- M1: this wave's Er/Ei rows (d-half) ----
    const _Float16* ABh = AB + (size_t)h * 2048;
    int j0 = wid * 8 + qq * 2;
    #pragma unroll
    for (int e = 0; e < 2; ++e) {       // e=0: Re rows, e=1: Im rows
        half8 af = *(const half8*)&ABh[(e * 32 + wid * 16 + ln) * 32 + qq * 8];
        #pragma unroll
        for (int nb = 0; nb < 4; ++nb) {
            float4v acc = (float4v){0.f, 0.f, 0.f, 0.f};
            acc = __builtin_amdgcn_mfma_f32_16x16x32_f16(af, uf[nb], acc, 0, 0, 0);
            unsigned p0 = pack_f16x2(acc[0], acc[1]);
            unsigned p1 = pack_f16x2(acc[2], acc[3]);
            *(uint2*)&El[(nb * 16 + ln) * EP + e * 16 + j0] = make_uint2(p0, p1);
        }
    }
    // own-wave write->read: DS ops drain, no cross-wave dependency yet
    asm volatile("s_waitcnt lgkmcnt(0)" ::: "memory");
    __builtin_amdgcn_sched_barrier(0);

    // ---- packed-fp16 scan over chunks (lane = c), own 8 pairs ----
    int c = lane;
    unsigned sr[8], si[8];
    {
        const unsigned* rp = &El[c * EP + wid * 8];
        uint4 r0 = *(const uint4*)rp;
        uint4 r1 = *(const uint4*)(rp + 4);
        uint4 i0 = *(const uint4*)(rp + 16);
        uint4 i1 = *(const uint4*)(rp + 20);
        sr[0]=r0.x; sr[1]=r0.y; sr[2]=r0.z; sr[3]=r0.w;
        sr[4]=r1.x; sr[5]=r1.y; sr[6]=r1.z; sr[7]=r1.w;
        si[0]=i0.x; si[1]=i0.y; si[2]=i0.z; si[3]=i0.w;
        si[4]=i1.x; si[5]=i1.y; si[6]=i1.z; si[7]=i1.w;
    }
    const unsigned* mpb = WPh + (size_t)h * 6 * 32;
    #pragma unroll
    for (int st = 0; st < 6; ++st) {
        int off = 1 << st;
        int src = (c - off) & 63;
        bool act = c >= off;
        const unsigned* mp = mpb + st * 32 + wid * 8;
        #pragma unroll
        for (int jj = 0; jj < 8; ++jj) {
            unsigned prp = (unsigned)__shfl((int)sr[jj], src);
            unsigned pip = (unsigned)__shfl((int)si[jj], src);
            if (!act) { prp = 0u; pip = 0u; }
            unsigned mru = mp[jj];
            unsigned miu = mp[16 + jj];
            unsigned min_ = miu ^ 0x80008000u;          // -Mi via sign flip
            half2v pr = *(half2v*)&prp, pi = *(half2v*)&pip;
            half2v Mr = *(half2v*)&mru, Mi = *(half2v*)&miu, Mni = *(half2v*)&min_;
            half2v s_r = *(half2v*)&sr[jj], s_i = *(half2v*)&si[jj];
            half2v nr = pk_fma16(pr, Mr, pk_fma16(pi, Mni, s_r));
            half2v ni = pk_fma16(pr, Mi, pk_fma16(pi, Mr,  s_i));
            sr[jj] = *(unsigned*)&nr; si[jj] = *(unsigned*)&ni;
        }
    }
    {   // exclusive shift: carry entering chunk c = S_{c-1}; lane 0 -> 0
        int srcm1 = (c - 1) & 63;
        #pragma unroll
        for (int jj = 0; jj < 8; ++jj) {
            unsigned a0 = (unsigned)__shfl((int)sr[jj], srcm1);
            unsigned b0 = (unsigned)__shfl((int)si[jj], srcm1);
            if (c == 0) { a0 = 0u; b0 = 0u; }
            sr[jj] = a0; si[jj] = b0;
        }
    }
    {   // carries back to same El slots
        unsigned* wp = &El[c * EP + wid * 8];
        *(uint4*)wp        = make_uint4(sr[0], sr[1], sr[2], sr[3]);
        *(uint4*)(wp + 4)  = make_uint4(sr[4], sr[5], sr[6], sr[7]);
        *(uint4*)(wp + 16) = make_uint4(si[0], si[1], si[2], si[3]);
        *(uint4*)(wp + 20) = make_uint4(si[4], si[5], si[6], si[7]);
    }
    // prefetch FK for epilogue; latency hides under barrier + M2
    const unsigned* fgh = FKf + (size_t)h * L_;
    uint4 fkp[2][2];
    #pragma unroll
    for (int nbi = 0; nbi < 2; ++nbi) {
        int col = (2 * wid + nbi) * 16 + ln;
        fkp[nbi][0] = *(const uint4*)&fgh[col * 32 + qq * 4];
        fkp[nbi][1] = *(const uint4*)&fgh[col * 32 + 16 + qq * 4];
    }
    __syncthreads();

    // ---- M2: y_pre = [T_f | Qr | -Qi] @ [U; Sr; Si], this wave's 2 col-tiles ----
    const _Float16* CBh = CB + (size_t)h * 3072;
    float4v acc2[2][2];
    #pragma unroll
    for (int mb = 0; mb < 2; ++mb)
        #pragma unroll
        for (int nbi = 0; nbi < 2; ++nbi)
            acc2[mb][nbi] = (float4v){0.f, 0.f, 0.f, 0.f};
    #pragma unroll
    for (int ks = 0; ks < 3; ++ks) {
        half8 a2[2];
        a2[0] = *(const half8*)&CBh[(ln)      * 96 + ks * 32 + qq * 8];
        a2[1] = *(const half8*)&CBh[(16 + ln) * 96 + ks * 32 + qq * 8];
        #pragma unroll
        for (int nbi = 0; nbi < 2; ++nbi) {
            int col = (2 * wid + nbi) * 16 + ln;
            half8 bfv;
            if (ks == 0) bfv = uf[2 * wid + nbi];
            else {
                int off = (ks == 1) ? 0 : 16;
                bfv = *(const half8*)&El[col * EP + off + qq * 4];
            }
            acc2[0][nbi] = __builtin_amdgcn_mfma_f32_16x16x32_f16(a2[0], bfv, acc2[0][nbi], 0, 0, 0);
            acc2[1][nbi] = __builtin_amdgcn_mfma_f32_16x16x32_f16(a2[1], bfv, acc2[1][nbi], 0, 0, 0);
        }
    }

    // ---- epilogue: y = y_pre + c0*u + c1*f + k0, fast gelu, pack bf16 ----
    float f0; { f0 = unpack_bf16x2(fgh[0]).x; }
    float c0v = Dp[h] - 0.5f * f0;
    float c1v = -0.5f * ug[0];
    #pragma unroll
    for (int nbi = 0; nbi < 2; ++nbi) {
        int col = (2 * wid + nbi) * 16 + ln;
        #pragma unroll
        for (int mb = 0; mb < 2; ++mb) {
            int l0 = col * 32 + mb * 16 + qq * 4;
            float4 u4 = *(const float4*)(ug + l0);
            uint4 fkv = fkp[nbi][mb];
            float us[4] = {u4.x, u4.y, u4.z, u4.w};
            unsigned fs[4] = {fkv.x, fkv.y, fkv.z, fkv.w};
            float g[4];
            #pragma unroll
            for (int r = 0; r < 4; ++r) {
                float2 fk = unpack_bf16x2(fs[r]);
                float yv = acc2[mb][nbi][r] + fmaf(c0v, us[r], fmaf(c1v, fk.x, fk.y));
                g[r] = gelu_fast(yv);
            }
            uint2 yo;
            yo.x = pack_bf16x2(g[0], g[1]);
            yo.y = pack_bf16x2(g[2], g[3]);
            *(uint2*)((short*)y + (size_t)(b * H_ + h) * L_ + l0) = yo;
        }
    }
}

// ---------------- transpose y[b][f][l] -> yT[b][l][f] (bf16) ----------------
__global__ __launch_bounds__(256) void transpose_y_kernel(
        const __hip_bfloat16* __restrict__ y, __hip_bfloat16* __restrict__ yT) {
    __shared__ short tile[64][72];
    int l0 = blockIdx.x * 64, f0 = blockIdx.y * 64, b = blockIdx.z;
    int t = threadIdx.x;
    int row = t >> 3, col8 = (t & 7) * 8;
    const short* yg = (const short*)y + (size_t)b * H_ * L_;
    #pragma unroll
    for (int r2 = 0; r2 < 64; r2 += 32)
        *(uint4*)&tile[row + r2][col8] =
            *(const uint4*)&yg[(size_t)(f0 + row + r2) * L_ + l0 + col8];
    __syncthreads();
    short* og = (short*)yT + (size_t)b * L_ * H_;
    #pragma unroll
    for (int r2 = 0; r2 < 64; r2 += 32) {
        int lrow = row + r2;
        short v[8];
        #pragma unroll
        for (int j = 0; j < 8; ++j) v[j] = tile[col8 + j][lrow];
        *(uint4*)&og[(size_t)(l0 + lrow) * H_ + f0 + col8] = *(uint4*)v;
    }
}

// ---------------- gemm: out[b,h,l] = sum_f W[h,f] * yT[b,l,f] + bias[h] ----------------
__global__ __launch_bounds__(256) void gemm_kernel(
        const __hip_bfloat16* __restrict__ Wb, const __hip_bfloat16* __restrict__ yT,
        const float* __restrict__ bias, float* __restrict__ out) {
    __shared__ __align__(16) short As[128 * 32];
    __shared__ __align__(16) short Bs[128 * 32];
    int l0 = blockIdx.x * 128;
    int h0 = blockIdx.y * 128;
    int b  = blockIdx.z;
    int t    = threadIdx.x;
    int lane = t & 63, wave = t >> 6;
    int m_off = (wave >> 1) * 64, n_off = (wave & 1) * 64;
    int quad = lane >> 4, ln = lane & 15;

    float4v acc[4][4];
    #pragma unroll
    for (int mt = 0; mt < 4; ++mt)
        #pragma unroll
        for (int nt = 0; nt < 4; ++nt)
            acc[mt][nt] = (float4v){0.f, 0.f, 0.f, 0.f};

    const short* Wg = (const short*)Wb;
    const short* Yg = (const short*)(yT + (size_t)b * L_ * H_);

    int r  = t >> 2;
    int qd = t & 3;

    for (int kt = 0; kt < 16; ++kt) {
        int k0 = kt * 32;
        load_lds16(Wg + (h0 + r)      * 512 + k0 + qd * 8, &As[t * 8]);
        load_lds16(Wg + (h0 + r + 64) * 512 + k0 + qd * 8, &As[(t + 256) * 8]);
        load_lds16(Yg + (size_t)(l0 + r)      * 512 + k0 + qd * 8, &Bs[t * 8]);
        load_lds16(Yg + (size_t)(l0 + r + 64) * 512 + k0 + qd * 8, &Bs[(t + 256) * 8]);
        __syncthreads();

        short8 af[4], bf[4];
        #pragma unroll
        for (int mt = 0; mt < 4; ++mt)
            af[mt] = *(const short8*)&As[(m_off + mt * 16 + ln) * 32 + quad * 8];
        #pragma unroll
        for (int nt = 0; nt < 4; ++nt)
            bf[nt] = *(const short8*)&Bs[(n_off + nt * 16 + ln) * 32 + quad * 8];
        #pragma unroll
        for (int mt = 0; mt < 4; ++mt)
            #pragma unroll
            for (int nt = 0; nt < 4; ++nt)
                acc[mt][nt] = __builtin_amdgcn_mfma_f32_16x16x32_bf16(
                    af[mt], bf[nt], acc[mt][nt], 0, 0, 0);
        __syncthreads();
    }

    #pragma unroll
    for (int mt = 0; mt < 4; ++mt) {
        #pragma unroll
        for (int nt = 0; nt < 4; ++nt) {
            int hh = h0 + m_off + mt * 16 + quad * 4;
            int ll = l0 + n_off + nt * 16 + ln;
            #pragma unroll
            for (int r2 = 0; r2 < 4; ++r2)
                out[((size_t)(b * H_ + hh + r2)) * L_ + ll] = acc[mt][nt][r2] + bias[hh + r2];
        }
    }
}

extern "C" void kernel_launch(void* const* d_in, const int* in_sizes, int n_in,
                              void* d_out, int out_size, void* d_ws, size_t ws_size,
                              hipStream_t stream) {
    const float* u    = (const float*)d_in[0];
    const float* a    = (const float*)d_in[1];
    const float* th   = (const float*)d_in[2];
    const float* bb   = (const float*)d_in[3];
    const float* cc   = (const float*)d_in[4];
    const float* x0   = (const float*)d_in[5];
    const float* Dp   = (const float*)d_in[6];
    const float* W    = (const float*)d_in[7];
    const float* bias = (const float*)d_in[8];
    float* out = (float*)d_out;
    char* ws = (char*)d_ws;

    // layout: FKf 4M @0 | yT 16M @4M | y 16M @20M | Wb 0.5M @36M | AB 2M @37M |
    //         CB 3M @39M | params @42M: aT,thT,qT,gxT (4x64KB) + WPh fp16 (384KB)
    unsigned*       FKf = (unsigned*)ws;
    __hip_bfloat16* yT  = (__hip_bfloat16*)(ws + (4ull  << 20));
    __hip_bfloat16* y   = (__hip_bfloat16*)(ws + (20ull << 20));
    __hip_bfloat16* Wb  = (__hip_bfloat16*)(ws + (36ull << 20));
    _Float16*       AB  = (_Float16*)(ws + (37ull << 20));
    _Float16*       CB  = (_Float16*)(ws + (39ull << 20));
    float* pbase = (float*)(ws + (42ull << 20));
    float *aT  = pbase,           *thT = pbase + 16384, *qT = pbase + 2*16384,
          *gxT = pbase + 3*16384;
    _Float16* WPh = (_Float16*)(pbase + 4*16384);

    hipLaunchKernelGGL(cast_prep_kernel,  dim3(1024),      dim3(256), 0, stream,
                       W, Wb, a, th, bb, cc, x0, aT, thT, qT, gxT, WPh);
    hipLaunchKernelGGL(fk_kernel,         dim3(L_/LCF, 8), dim3(256), 0, stream,
                       aT, thT, qT, gxT, FKf);
    hipLaunchKernelGGL(prep2_kernel,      dim3(H_),        dim3(256), 0, stream,
                       aT, thT, qT, FKf, AB, CB);
    hipLaunchKernelGGL(scan_mfma_kernel,  dim3(H_, B_),    dim3(128), 0, stream,
                       u, AB, CB, (const unsigned*)WPh, Dp, FKf, y);
    hipLaunchKernelGGL(transpose_y_kernel,dim3(32, 8, 8),  dim3(256), 0, stream, y, yT);
    hipLaunchKernelGGL(gemm_kernel,       dim3(16, 4, 8),  dim3(256), 0, stream,
                       Wb, yT, bias, out);
}

// Round 4
// 171.875 us; speedup vs baseline: 1.2815x; 1.0346x over previous
//
#include <hip/hip_runtime.h>
#include <hip/hip_bf16.h>

#define B_  8
#define H_  512
#define L_  2048
#define D2_ 32
#define NC_ 64
#define LC_ 32    // L_/NC_
#define EP  36    // E_lds row pitch in u32 (16B-aligned rows)

typedef __attribute__((ext_vector_type(8))) short short8;     // 8 bf16 (4 VGPRs)
typedef __attribute__((ext_vector_type(8))) _Float16 half8;   // 8 fp16 (4 VGPRs)
typedef __attribute__((ext_vector_type(2))) _Float16 half2v;  // packed fp16 (v_pk_*)
typedef __attribute__((ext_vector_type(4))) float float4v;    // 4 fp32 acc

__device__ __forceinline__ half2v pk_fma16(half2v a, half2v b, half2v c) {
    return __builtin_elementwise_fma(a, b, c);
}

// tanh-form GELU: max |err| vs exact ~3e-4, far below bf16 y-storage ulp.
__device__ __forceinline__ float gelu_fast(float x) {
    float q = x * fmaf(0.044715f, x * x, 1.0f);
    float s = __expf(-1.5957691216057308f * q);   // e^{-2*0.79788456*q}
    return __fdividef(x, 1.0f + s);               // x * sigmoid(2w)
}

__device__ __forceinline__ unsigned pack_bf16x2(float x, float y) {
    __hip_bfloat162 p = __float22bfloat162_rn(make_float2(x, y));
    return *(unsigned*)&p;
}
__device__ __forceinline__ float2 unpack_bf16x2(unsigned v) {
    __hip_bfloat162 p = *(__hip_bfloat162*)&v;
    return __bfloat1622float2(p);
}
__device__ __forceinline__ unsigned pack_f16x2(float x, float y) {
    auto v = __builtin_amdgcn_cvt_pkrtz(x, y);    // v_cvt_pkrtz_f16_f32
    return *(unsigned*)&v;
}

__device__ __forceinline__ void load_lds16(const void* g, void* l) {
    __builtin_amdgcn_global_load_lds((const __attribute__((address_space(1))) unsigned int*)g,
                                     (__attribute__((address_space(3))) unsigned int*)l, 16, 0, 0);
}

// ---------------- cast W -> bf16, fused param prep ----------------
// WPh (fp16): per-h chunk-combine multipliers P^(2^k), P = w^32, k=0..5.
// u32 view: [(h*6+k)*32 + j] = {Mr_2j, Mr_2j+1}; [+16+j] = {Mi_2j, Mi_2j+1}.
__global__ void cast_prep_kernel(const float* __restrict__ W, __hip_bfloat16* __restrict__ Wb,
                                 const float* __restrict__ a, const float* __restrict__ th,
                                 const float* __restrict__ bb, const float* __restrict__ cc,
                                 const float* __restrict__ x0,
                                 float* __restrict__ aT, float* __restrict__ thT,
                                 float* __restrict__ qT, float* __restrict__ gxT,
                                 _Float16* __restrict__ WPh) {
    int tid = blockIdx.x * 256 + threadIdx.x;   // 262144
    Wb[tid] = __float2bfloat16(W[tid]);
    if (tid < H_ * D2_) {                        // tid = d*H + h (d-major)
        int h = tid & (H_ - 1);
        int d = tid >> 9;
        const float T = 1.0f / (float)(L_ - 1);
        float av = -fabsf(a[h * D2_ + d]);
        float tv = th[h * D2_ + d];
        float q  = bb[h * D2_ + d] * cc[h * D2_ + d];
        aT[tid]  = av;
        thT[tid] = tv;
        qT[tid]  = q;
        gxT[tid] = 2.0f * cc[h * D2_ + d] * x0[h * D2_ + d];
        #pragma unroll
        for (int k = 0; k < 6; ++k) {
            float len = (float)(32 << k);        // 32 * 2^k steps
            float e2  = __expf(av * T * len);
            float an  = tv * T * len;
            WPh[((size_t)h * 6 + k) * 64 + d]      = (_Float16)(e2 * __cosf(an));
            WPh[((size_t)h * 6 + k) * 64 + 32 + d] = (_Float16)(e2 * __sinf(an));
        }
    }
}

// ---------------- fkprep: fk (SSM kernel f, k0) + MFMA operand build, one block per h ----
// Phase 1 (fk): thread (q4 = t&3, lc = t>>2): d in [q4*8, q4*8+8), l in [lc*32, lc*32+32).
//   FKf[h*L + l] = bf16x2{ f[h,l], k0[h,l] }; f[0..31] also kept in LDS (fp32).
// Phase 2 (prep2): AB[h][m][i] (64x32): m<32: Re(W_d^{31-i}); m>=32: Im(W_d^{31-i}).
//   CB[h][i][k] (32x96): k<32: Toeplitz f[i-k] (k<=i else 0);
//                        k in [32,64): d=k-32:  qs_d*Re(W_d^{i+1});
//                        k in [64,96): d=k-64: -qs_d*Im(W_d^{i+1}).
__global__ __launch_bounds__(256) void fkprep_kernel(
        const float* __restrict__ aT, const float* __restrict__ thT,
        const float* __restrict__ qT, const float* __restrict__ gxT,
        unsigned* __restrict__ FKf, _Float16* __restrict__ AB,
        _Float16* __restrict__ CB) {
    __shared__ float f_lds[32];
    int h = blockIdx.x;
    int t = threadIdx.x;
    int q4 = t & 3, lc = t >> 2;
    const float T = 1.0f / (float)(L_ - 1);
    float z0 = T * (float)(lc * 32);
    float pr[8], pi[8], wr[8], wi[8], qd[8], gx[8];
    #pragma unroll
    for (int j = 0; j < 8; ++j) {
        int idx = (q4 * 8 + j) * H_ + h;
        float aa = aT[idx], tv = thT[idx];
        float e0 = __expf(aa * z0);
        pr[j] = e0 * __cosf(tv * z0);
        pi[j] = e0 * __sinf(tv * z0);
        float e1 = __expf(aa * T);
        wr[j] = e1 * __cosf(tv * T);
        wi[j] = e1 * __sinf(tv * T);
        qd[j] = qT[idx];
        gx[j] = gxT[idx];
    }
    for (int i = 0; i < 32; ++i) {
        float fa = 0.f, ka = 0.f;
        #pragma unroll
        for (int j = 0; j < 8; ++j) {
            fa = fmaf(qd[j], pr[j], fa);
            ka = fmaf(gx[j], pr[j], ka);
            float nr = fmaf(pr[j], wr[j], -(pi[j] * wi[j]));
            float ni = fmaf(pr[j], wi[j],  (pi[j] * wr[j]));
            pr[j] = nr; pi[j] = ni;
        }
        fa += __shfl_xor(fa, 1); fa += __shfl_xor(fa, 2);
        ka += __shfl_xor(ka, 1); ka += __shfl_xor(ka, 2);
        if (q4 == 0) {
            float fv = 2.0f * T * fa;
            FKf[(size_t)h * L_ + lc * 32 + i] = pack_bf16x2(fv, ka);
            if (lc == 0) f_lds[i] = fv;
        }
    }
    __syncthreads();
    // ---- phase 2: operand matrices (fp16) ----
    for (int e = t; e < 64 * 32; e += 256) {
        int m = e >> 5, i = e & 31;
        int d = m & 31;
        float av = aT[d * H_ + h], tv = thT[d * H_ + h];
        float z  = T * (float)(31 - i);
        float ex = __expf(av * z);
        float v  = (m < 32) ? ex * __cosf(tv * z) : ex * __sinf(tv * z);
        AB[(size_t)h * 2048 + e] = (_Float16)v;
    }
    for (int e = t; e < 32 * 96; e += 256) {
        int i = e / 96, k = e - i * 96;
        float v = 0.f;
        if (k < 32) {
            if (k <= i) v = f_lds[i - k];
        } else {
            int d = (k < 64) ? k - 32 : k - 64;
            float av = aT[d * H_ + h], tv = thT[d * H_ + h];
            float qs = 2.0f * T * qT[d * H_ + h];
            float z  = T * (float)(i + 1);
            float ex = __expf(av * z);
            v = (k < 64) ? qs * ex * __cosf(tv * z) : -qs * ex * __sinf(tv * z);
        }
        CB[(size_t)h * 3072 + e] = (_Float16)v;
    }
}

// ---------------- scan_mfma v2: 2 waves per (b,h), fp16 MFMA + packed-fp16 scan ----
// Wave wid owns d in [wid*16, wid*16+16)  (pairs j in [wid*8, wid*8+8)):
//   M1 (8 mfma f16): its Er/Ei rows -> El (fp16x2 pairs)
//   lgkmcnt(0) (own-wave data only, no barrier needed)
//   packed-fp16 Hillis-Steele over 64 chunks (1 shfl per pair) -> carries
//   single __syncthreads
//   M2 (12 mfma f16): its 2 column-tiles; epilogue: its 32 columns.
__global__ __launch_bounds__(128, 6) void scan_mfma_kernel(
        const float* __restrict__ u, const _Float16* __restrict__ AB,
        const _Float16* __restrict__ CB, const unsigned* __restrict__ WPh,
        const float* __restrict__ Dp, const unsigned* __restrict__ FKf,
        __hip_bfloat16* __restrict__ y) {
    __shared__ __align__(16) unsigned El[64 * EP];
    int wid = threadIdx.x >> 6, lane = threadIdx.x & 63;
    int h = blockIdx.x, b = blockIdx.y;
    int ln = lane & 15, qq = lane >> 4;
    const float* ug = u + (size_t)(b * H_ + h) * L_;

    // ---- U fragments (fp16), all 4 column-tiles (needed as M1 B-operand) ----
    half8 uf[4];
    #pragma unroll
    for (int nb = 0; nb < 4; ++nb) {
        const float* p = ug + (nb * 16 + ln) * 32 + qq * 8;
        float4 a0 = *(const float4*)p;
        float4 a1 = *(const float4*)(p + 4);
        unsigned* vp = (unsigned*)&uf[nb];
        vp[0] = pack_f16x2(a0.x, a0.y);
        vp[1] = pack_f16x2(a0.z, a0.w);
        vp[2] = pack_f16x2(a1.x, a1.y);
        vp[3] = pack_f16x2(a1.z, a1.w);
    }

    // ---- M1: this wave's Er/Ei rows (d-half) ----
    const _Float16* ABh = AB + (size_t)h * 2048;
    int j0 = wid * 8 + qq * 2;
    #pragma unroll
    for (int e = 0; e < 2; ++e) {       // e=0: Re rows, e=1: Im rows
        half8 af = *(const half8*)&ABh[(e * 32 + wid * 16 + ln) * 32 + qq * 8];
        #pragma unroll
        for (int nb = 0; nb < 4; ++nb) {
            float4v acc = (float4v){0.f, 0.f, 0.f, 0.f};
            acc = __builtin_amdgcn_mfma_f32_16x16x32_f16(af, uf[nb], acc, 0, 0, 0);
            unsigned p0 = pack_f16x2(acc[0], acc[1]);
            unsigned p1 = pack_f16x2(acc[2], acc[3]);
            *(uint2*)&El[(nb * 16 + ln) * EP + e * 16 + j0] = make_uint2(p0, p1);
        }
    }
    // own-wave write->read: DS ops drain, no cross-wave dependency yet
    asm volatile("s_waitcnt lgkmcnt(0)" ::: "memory");
    __builtin_amdgcn_sched_barrier(0);

    // ---- packed-fp16 scan over chunks (lane = c), own 8 pairs ----
    int c = lane;
    unsigned sr[8], si[8];
    {
        const unsigned* rp = &El[c * EP + wid * 8];
        uint4 r0 = *(const uint4*)rp;
        uint4 r1 = *(const uint4*)(rp + 4);
        uint4 i0 = *(const uint4*)(rp + 16);
        uint4 i1 = *(const uint4*)(rp + 20);
        sr[0]=r0.x; sr[1]=r0.y; sr[2]=r0.z; sr[3]=r0.w;
        sr[4]=r1.x; sr[5]=r1.y; sr[6]=r1.z; sr[7]=r1.w;
        si[0]=i0.x; si[1]=i0.y; si[2]=i0.z; si[3]=i0.w;
        si[4]=i1.x; si[5]=i1.y; si[6]=i1.z; si[7]=i1.w;
    }
    const unsigned* mpb = WPh + (size_t)h * 6 * 32;
    #pragma unroll
    for (int st = 0; st < 6; ++st) {
        int off = 1 << st;
        int src = (c - off) & 63;
        bool act = c >= off;
        const unsigned* mp = mpb + st * 32 + wid * 8;
        #pragma unroll
        for (int jj = 0; jj < 8; ++jj) {
            unsigned prp = (unsigned)__shfl((int)sr[jj], src);
            unsigned pip = (unsigned)__shfl((int)si[jj], src);
            if (!act) { prp = 0u; pip = 0u; }
            unsigned mru = mp[jj];
            unsigned miu = mp[16 + jj];
            unsigned min_ = miu ^ 0x80008000u;          // -Mi via sign flip
            half2v pr = *(half2v*)&prp, pi = *(half2v*)&pip;
            half2v Mr = *(half2v*)&mru, Mi = *(half2v*)&miu, Mni = *(half2v*)&min_;
            half2v s_r = *(half2v*)&sr[jj], s_i = *(half2v*)&si[jj];
            half2v nr = pk_fma16(pr, Mr, pk_fma16(pi, Mni, s_r));
            half2v ni = pk_fma16(pr, Mi, pk_fma16(pi, Mr,  s_i));
            sr[jj] = *(unsigned*)&nr; si[jj] = *(unsigned*)&ni;
        }
    }
    {   // exclusive shift: carry entering chunk c = S_{c-1}; lane 0 -> 0
        int srcm1 = (c - 1) & 63;
        #pragma unroll
        for (int jj = 0; jj < 8; ++jj) {
            unsigned a0 = (unsigned)__shfl((int)sr[jj], srcm1);
            unsigned b0 = (unsigned)__shfl((int)si[jj], srcm1);
            if (c == 0) { a0 = 0u; b0 = 0u; }
            sr[jj] = a0; si[jj] = b0;
        }
    }
    {   // carries back to same El slots
        unsigned* wp = &El[c * EP + wid * 8];
        *(uint4*)wp        = make_uint4(sr[0], sr[1], sr[2], sr[3]);
        *(uint4*)(wp + 4)  = make_uint4(sr[4], sr[5], sr[6], sr[7]);
        *(uint4*)(wp + 16) = make_uint4(si[0], si[1], si[2], si[3]);
        *(uint4*)(wp + 20) = make_uint4(si[4], si[5], si[6], si[7]);
    }
    // prefetch FK for epilogue; latency hides under barrier + M2
    const unsigned* fgh = FKf + (size_t)h * L_;
    uint4 fkp[2][2];
    #pragma unroll
    for (int nbi = 0; nbi < 2; ++nbi) {
        int col = (2 * wid + nbi) * 16 + ln;
        fkp[nbi][0] = *(const uint4*)&fgh[col * 32 + qq * 4];
        fkp[nbi][1] = *(const uint4*)&fgh[col * 32 + 16 + qq * 4];
    }
    __syncthreads();

    // ---- M2: y_pre = [T_f | Qr | -Qi] @ [U; Sr; Si], this wave's 2 col-tiles ----
    const _Float16* CBh = CB + (size_t)h * 3072;
    float4v acc2[2][2];
    #pragma unroll
    for (int mb = 0; mb < 2; ++mb)
        #pragma unroll
        for (int nbi = 0; nbi < 2; ++nbi)
            acc2[mb][nbi] = (float4v){0.f, 0.f, 0.f, 0.f};
    #pragma unroll
    for (int ks = 0; ks < 3; ++ks) {
        half8 a2[2];
        a2[0] = *(const half8*)&CBh[(ln)      * 96 + ks * 32 + qq * 8];
        a2[1] = *(const half8*)&CBh[(16 + ln) * 96 + ks * 32 + qq * 8];
        #pragma unroll
        for (int nbi = 0; nbi < 2; ++nbi) {
            int col = (2 * wid + nbi) * 16 + ln;
            half8 bfv;
            if (ks == 0) bfv = uf[2 * wid + nbi];
            else {
                int off = (ks == 1) ? 0 : 16;
                bfv = *(const half8*)&El[col * EP + off + qq * 4];
            }
            acc2[0][nbi] = __builtin_amdgcn_mfma_f32_16x16x32_f16(a2[0], bfv, acc2[0][nbi], 0, 0, 0);
            acc2[1][nbi] = __builtin_amdgcn_mfma_f32_16x16x32_f16(a2[1], bfv, acc2[1][nbi], 0, 0, 0);
        }
    }

    // ---- epilogue: y = y_pre + c0*u + c1*f + k0, fast gelu, pack bf16 ----
    float f0; { f0 = unpack_bf16x2(fgh[0]).x; }
    float c0v = Dp[h] - 0.5f * f0;
    float c1v = -0.5f * ug[0];
    #pragma unroll
    for (int nbi = 0; nbi < 2; ++nbi) {
        int col = (2 * wid + nbi) * 16 + ln;
        #pragma unroll
        for (int mb = 0; mb < 2; ++mb) {
            int l0 = col * 32 + mb * 16 + qq * 4;
            float4 u4 = *(const float4*)(ug + l0);
            uint4 fkv = fkp[nbi][mb];
            float us[4] = {u4.x, u4.y, u4.z, u4.w};
            unsigned fs[4] = {fkv.x, fkv.y, fkv.z, fkv.w};
            float g[4];
            #pragma unroll
            for (int r = 0; r < 4; ++r) {
                float2 fk = unpack_bf16x2(fs[r]);
                float yv = acc2[mb][nbi][r] + fmaf(c0v, us[r], fmaf(c1v, fk.x, fk.y));
                g[r] = gelu_fast(yv);
            }
            uint2 yo;
            yo.x = pack_bf16x2(g[0], g[1]);
            yo.y = pack_bf16x2(g[2], g[3]);
            *(uint2*)((short*)y + (size_t)(b * H_ + h) * L_ + l0) = yo;
        }
    }
}

// ---------------- transpose y[b][f][l] -> yT[b][l][f] (bf16) ----------------
__global__ __launch_bounds__(256) void transpose_y_kernel(
        const __hip_bfloat16* __restrict__ y, __hip_bfloat16* __restrict__ yT) {
    __shared__ short tile[64][72];
    int l0 = blockIdx.x * 64, f0 = blockIdx.y * 64, b = blockIdx.z;
    int t = threadIdx.x;
    int row = t >> 3, col8 = (t & 7) * 8;
    const short* yg = (const short*)y + (size_t)b * H_ * L_;
    #pragma unroll
    for (int r2 = 0; r2 < 64; r2 += 32)
        *(uint4*)&tile[row + r2][col8] =
            *(const uint4*)&yg[(size_t)(f0 + row + r2) * L_ + l0 + col8];
    __syncthreads();
    short* og = (short*)yT + (size_t)b * L_ * H_;
    #pragma unroll
    for (int r2 = 0; r2 < 64; r2 += 32) {
        int lrow = row + r2;
        short v[8];
        #pragma unroll
        for (int j = 0; j < 8; ++j) v[j] = tile[col8 + j][lrow];
        *(uint4*)&og[(size_t)(l0 + lrow) * H_ + f0 + col8] = *(uint4*)v;
    }
}

// ---------------- gemm: out[b,h,l] = sum_f W[h,f] * yT[b,l,f] + bias[h] ----------------
// 64x128 tile, grid 1024 blocks (4/CU, 16 waves/CU) — was 128x128 @ 512 blocks (2/CU),
// which starved the 2-barrier structure of inter-block overlap.
__global__ __launch_bounds__(256) void gemm_kernel(
        const __hip_bfloat16* __restrict__ Wb, const __hip_bfloat16* __restrict__ yT,
        const float* __restrict__ bias, float* __restrict__ out) {
    __shared__ __align__(16) short As[64 * 32];
    __shared__ __align__(16) short Bs[128 * 32];
    int l0 = blockIdx.x * 128;
    int h0 = blockIdx.y * 64;
    int b  = blockIdx.z;
    int t    = threadIdx.x;
    int lane = t & 63, wave = t >> 6;
    int m_off = (wave >> 1) * 32, n_off = (wave & 1) * 64;
    int quad = lane >> 4, ln = lane & 15;

    float4v acc[2][4];
    #pragma unroll
    for (int mt = 0; mt < 2; ++mt)
        #pragma unroll
        for (int nt = 0; nt < 4; ++nt)
            acc[mt][nt] = (float4v){0.f, 0.f, 0.f, 0.f};

    const short* Wg = (const short*)Wb;
    const short* Yg = (const short*)(yT + (size_t)b * L_ * H_);

    int r  = t >> 2;       // 0..63
    int qd = t & 3;

    for (int kt = 0; kt < 16; ++kt) {
        int k0 = kt * 32;
        load_lds16(Wg + (h0 + r) * 512 + k0 + qd * 8, &As[t * 8]);
        load_lds16(Yg + (size_t)(l0 + r)      * 512 + k0 + qd * 8, &Bs[t * 8]);
        load_lds16(Yg + (size_t)(l0 + r + 64) * 512 + k0 + qd * 8, &Bs[(t + 256) * 8]);
        __syncthreads();

        short8 af[2], bf[4];
        #pragma unroll
        for (int mt = 0; mt < 2; ++mt)
            af[mt] = *(const short8*)&As[(m_off + mt * 16 + ln) * 32 + quad * 8];
        #pragma unroll
        for (int nt = 0; nt < 4; ++nt)
            bf[nt] = *(const short8*)&Bs[(n_off + nt * 16 + ln) * 32 + quad * 8];
        #pragma unroll
        for (int mt = 0; mt < 2; ++mt)
            #pragma unroll
            for (int nt = 0; nt < 4; ++nt)
                acc[mt][nt] = __builtin_amdgcn_mfma_f32_16x16x32_bf16(
                    af[mt], bf[nt], acc[mt][nt], 0, 0, 0);
        __syncthreads();
    }

    #pragma unroll
    for (int mt = 0; mt < 2; ++mt) {
        #pragma unroll
        for (int nt = 0; nt < 4; ++nt) {
            int hh = h0 + m_off + mt * 16 + quad * 4;
            int ll = l0 + n_off + nt * 16 + ln;
            #pragma unroll
            for (int r2 = 0; r2 < 4; ++r2)
                out[((size_t)(b * H_ + hh + r2)) * L_ + ll] = acc[mt][nt][r2] + bias[hh + r2];
        }
    }
}

extern "C" void kernel_launch(void* const* d_in, const int* in_sizes, int n_in,
                              void* d_out, int out_size, void* d_ws, size_t ws_size,
                              hipStream_t stream) {
    const float* u    = (const float*)d_in[0];
    const float* a    = (const float*)d_in[1];
    const float* th   = (const float*)d_in[2];
    const float* bb   = (const float*)d_in[3];
    const float* cc   = (const float*)d_in[4];
    const float* x0   = (const float*)d_in[5];
    const float* Dp   = (const float*)d_in[6];
    const float* W    = (const float*)d_in[7];
    const float* bias = (const float*)d_in[8];
    float* out = (float*)d_out;
    char* ws = (char*)d_ws;

    // layout: FKf 4M @0 | yT 16M @4M | y 16M @20M | Wb 0.5M @36M | AB 2M @37M |
    //         CB 3M @39M | params @42M: aT,thT,qT,gxT (4x64KB) + WPh fp16 (384KB)
    unsigned*       FKf = (unsigned*)ws;
    __hip_bfloat16* yT  = (__hip_bfloat16*)(ws + (4ull  << 20));
    __hip_bfloat16* y   = (__hip_bfloat16*)(ws + (20ull << 20));
    __hip_bfloat16* Wb  = (__hip_bfloat16*)(ws + (36ull << 20));
    _Float16*       AB  = (_Float16*)(ws + (37ull << 20));
    _Float16*       CB  = (_Float16*)(ws + (39ull << 20));
    float* pbase = (float*)(ws + (42ull << 20));
    float *aT  = pbase,           *thT = pbase + 16384, *qT = pbase + 2*16384,
          *gxT = pbase + 3*16384;
    _Float16* WPh = (_Float16*)(pbase + 4*16384);

    hipLaunchKernelGGL(cast_prep_kernel,  dim3(1024),      dim3(256), 0, stream,
                       W, Wb, a, th, bb, cc, x0, aT, thT, qT, gxT, WPh);
    hipLaunchKernelGGL(fkprep_kernel,     dim3(H_),        dim3(256), 0, stream,
                       aT, thT, qT, gxT, FKf, AB, CB);
    hipLaunchKernelGGL(scan_mfma_kernel,  dim3(H_, B_),    dim3(128), 0, stream,
                       u, AB, CB, (const unsigned*)WPh, Dp, FKf, y);
    hipLaunchKernelGGL(transpose_y_kernel,dim3(32, 8, 8),  dim3(256), 0, stream, y, yT);
    hipLaunchKernelGGL(gemm_kernel,       dim3(16, 8, 8),  dim3(256), 0, stream,
                       Wb, yT, bias, out);
}